// Round 5
// baseline (151.496 us; speedup 1.0000x reference)
//
#include <hip/hip_runtime.h>

#define FF 20
#define NI 190         // F*(F-1)/2
#define NIP 192        // padded
#define BB 4096
#define FD 320         // F*D
#define BPB 4          // batches per k_main block

// K1: W12p[320][192] = senet_w1[320][320] @ senet_w2[320][190], zero-padded cols
__global__ __launch_bounds__(192) void k_w12(const float* __restrict__ w1,
                                             const float* __restrict__ w2,
                                             float* __restrict__ W12p) {
    __shared__ float srow[FD];
    int r = blockIdx.x;
    for (int j = threadIdx.x; j < FD; j += 192) srow[j] = w1[r * FD + j];
    __syncthreads();
    int c = threadIdx.x;   // 0..191
    float acc = 0.f;
    if (c < NI) {
        for (int k = 0; k < FD; ++k) acc += srow[k] * w2[k * NI + c];
    }
    W12p[r * NIP + c] = acc;
}

// K2: w[4096][192] = z[4096][320] @ W12p[320][192]. 64x64 tiles, 4x4 per thread.
__global__ __launch_bounds__(256) void k_w(const float* __restrict__ z,
                                           const float* __restrict__ W12p,
                                           float* __restrict__ wout) {
    __shared__ float zT[32][68];
    __shared__ float Ws[32][64];
    int b0 = blockIdx.x * 64;
    int c0 = blockIdx.y * 64;
    int t = threadIdx.x;
    int tr = t >> 4, tc = t & 15;
    float acc[4][4];
#pragma unroll
    for (int i = 0; i < 4; ++i)
#pragma unroll
        for (int j = 0; j < 4; ++j) acc[i][j] = 0.f;

    for (int k0 = 0; k0 < FD; k0 += 32) {
#pragma unroll
        for (int s = 0; s < 2; ++s) {
            int task = t + s * 256;
            int row = task >> 3, ch = task & 7;
            float4 v = *(const float4*)&z[(b0 + row) * FD + k0 + ch * 4];
            zT[ch * 4 + 0][row] = v.x;
            zT[ch * 4 + 1][row] = v.y;
            zT[ch * 4 + 2][row] = v.z;
            zT[ch * 4 + 3][row] = v.w;
        }
#pragma unroll
        for (int s = 0; s < 2; ++s) {
            int task = t + s * 256;
            int kr = task >> 4, cq = task & 15;
            *(float4*)&Ws[kr][cq * 4] = *(const float4*)&W12p[(k0 + kr) * NIP + c0 + cq * 4];
        }
        __syncthreads();
#pragma unroll
        for (int k = 0; k < 32; ++k) {
            float4 zb = *(const float4*)&zT[k][tr * 4];
            float4 wv = *(const float4*)&Ws[k][tc * 4];
            float zz[4] = {zb.x, zb.y, zb.z, zb.w};
            float ww[4] = {wv.x, wv.y, wv.z, wv.w};
#pragma unroll
            for (int i = 0; i < 4; ++i)
#pragma unroll
                for (int j = 0; j < 4; ++j) acc[i][j] += zz[i] * ww[j];
        }
        __syncthreads();
    }
#pragma unroll
    for (int i = 0; i < 4; ++i) {
        float4 v = make_float4(acc[i][0], acc[i][1], acc[i][2], acc[i][3]);
        *(float4*)&wout[(b0 + tr * 4 + i) * NIP + c0 + tc * 4] = v;
    }
}

// K3: float4-gather weighted-sum-first. Block = 320 threads, BPB=4 batches.
// thread (bl, f, dq): gathers 38 x 64B rows as dwordx4 (4 lanes per row),
// accumulates weighted float4 per head, then 32x4 transform from LDS W.
#define SAC(bl, f, h, k) ((((bl) * FF + (f)) * 2 + (h)) * 17 + (k))
__global__ __launch_bounds__(320, 4) void k_main(const float* __restrict__ cb,   // [500000][16]
                                                 const float* __restrict__ Wt,   // [32][16]
                                                 const int* __restrict__ hidx,   // [2][B][NI]
                                                 const int* __restrict__ iidx,   // [20][19]
                                                 const float* __restrict__ wbuf, // [B][192]
                                                 float* __restrict__ out) {      // [B][20][16]
    __shared__ int s_i0[BPB][NI], s_i1[BPB][NI];
    __shared__ float s_w[BPB][NI];
    __shared__ int s_plist[FF * 19];
    __shared__ float s_W[32 * 16];
    __shared__ float s_acc[SAC(BPB - 1, FF - 1, 1, 16) + 1];

    int t = threadIdx.x;
    int b0 = blockIdx.x * BPB;

#pragma unroll
    for (int bl = 0; bl < BPB; ++bl) {
        if (t < NI) {
            s_i0[bl][t] = hidx[(b0 + bl) * NI + t];
            s_i1[bl][t] = hidx[(BB + b0 + bl) * NI + t];
            s_w[bl][t] = wbuf[(b0 + bl) * NIP + t];
        }
    }
    for (int j = t; j < FF * 19; j += 320) s_plist[j] = iidx[j];
    for (int j = t; j < 512; j += 320) s_W[j] = Wt[j];
    __syncthreads();

    int bl = t / 80;
    int r = t % 80;
    int f = r >> 2, dq = r & 3;

    const float4* cb4 = (const float4*)cb;
    const int* pl = &s_plist[f * 19];
    float4 a0 = make_float4(0.f, 0.f, 0.f, 0.f);
    float4 a1 = make_float4(0.f, 0.f, 0.f, 0.f);
#pragma unroll
    for (int j = 0; j < 19; ++j) {
        int p = pl[j];
        float wv = s_w[bl][p];
        float4 v0 = cb4[s_i0[bl][p] * 4 + dq];
        float4 v1 = cb4[s_i1[bl][p] * 4 + dq];
        a0.x += wv * v0.x; a0.y += wv * v0.y; a0.z += wv * v0.z; a0.w += wv * v0.w;
        a1.x += wv * v1.x; a1.y += wv * v1.y; a1.z += wv * v1.z; a1.w += wv * v1.w;
    }
    s_acc[SAC(bl, f, 0, dq * 4 + 0)] = a0.x;
    s_acc[SAC(bl, f, 0, dq * 4 + 1)] = a0.y;
    s_acc[SAC(bl, f, 0, dq * 4 + 2)] = a0.z;
    s_acc[SAC(bl, f, 0, dq * 4 + 3)] = a0.w;
    s_acc[SAC(bl, f, 1, dq * 4 + 0)] = a1.x;
    s_acc[SAC(bl, f, 1, dq * 4 + 1)] = a1.y;
    s_acc[SAC(bl, f, 1, dq * 4 + 2)] = a1.z;
    s_acc[SAC(bl, f, 1, dq * 4 + 3)] = a1.w;
    __syncthreads();

    // transform: out[b,f,dq*4+c] = sum_k acc0[k]*W[k][..] + acc1[k]*W[16+k][..]
    float4 rr = make_float4(0.f, 0.f, 0.f, 0.f);
#pragma unroll
    for (int k = 0; k < 16; ++k) {
        float c0 = s_acc[SAC(bl, f, 0, k)];
        float4 wv = *(const float4*)&s_W[k * 16 + dq * 4];
        rr.x += c0 * wv.x; rr.y += c0 * wv.y; rr.z += c0 * wv.z; rr.w += c0 * wv.w;
    }
#pragma unroll
    for (int k = 0; k < 16; ++k) {
        float c1 = s_acc[SAC(bl, f, 1, k)];
        float4 wv = *(const float4*)&s_W[(16 + k) * 16 + dq * 4];
        rr.x += c1 * wv.x; rr.y += c1 * wv.y; rr.z += c1 * wv.z; rr.w += c1 * wv.w;
    }
    *(float4*)&out[(b0 + bl) * FD + f * 16 + dq * 4] = rr;
}

extern "C" void kernel_launch(void* const* d_in, const int* in_sizes, int n_in,
                              void* d_out, int out_size, void* d_ws, size_t ws_size,
                              hipStream_t stream) {
    const float* origin = (const float*)d_in[0];  // (B, F, D) = z
    const float* cb     = (const float*)d_in[1];  // (500000, 16)
    const float* Wt     = (const float*)d_in[2];  // (32, 16)
    const float* w1     = (const float*)d_in[3];  // (320, 320)
    const float* w2     = (const float*)d_in[4];  // (320, 190)
    const int*   hidx   = (const int*)d_in[5];    // (2, B, 190)
    const int*   iidx   = (const int*)d_in[6];    // (20, 19)
    float* out = (float*)d_out;

    float* W12p = (float*)d_ws;           // 320*192 floats
    float* wbuf = W12p + FD * NIP;        // 4096*192 floats

    k_w12<<<FD, 192, 0, stream>>>(w1, w2, W12p);
    dim3 gw(BB / 64, 3);
    k_w<<<gw, 256, 0, stream>>>(origin, W12p, wbuf);
    k_main<<<BB / BPB, 320, 0, stream>>>(cb, Wt, hidx, iidx, wbuf, out);
}

// Round 6
// 145.663 us; speedup vs baseline: 1.0400x; 1.0400x over previous
//
#include <hip/hip_runtime.h>

#define FF 20
#define NI 190         // F*(F-1)/2
#define NIP 192        // padded
#define BB 4096
#define FD 320         // F*D

// K1: W12p[320][192] = senet_w1[320][320] @ senet_w2[320][190], zero-padded cols
__global__ __launch_bounds__(192) void k_w12(const float* __restrict__ w1,
                                             const float* __restrict__ w2,
                                             float* __restrict__ W12p) {
    __shared__ float srow[FD];
    int r = blockIdx.x;
    for (int j = threadIdx.x; j < FD; j += 192) srow[j] = w1[r * FD + j];
    __syncthreads();
    int c = threadIdx.x;   // 0..191
    float acc = 0.f;
    if (c < NI) {
        for (int k = 0; k < FD; ++k) acc += srow[k] * w2[k * NI + c];
    }
    W12p[r * NIP + c] = acc;
}

// K2: w[4096][192] = z[4096][320] @ W12p[320][192]. 64x64 tiles, 4x4 per thread.
__global__ __launch_bounds__(256) void k_w(const float* __restrict__ z,
                                           const float* __restrict__ W12p,
                                           float* __restrict__ wout) {
    __shared__ float zT[32][68];
    __shared__ float Ws[32][64];
    int b0 = blockIdx.x * 64;
    int c0 = blockIdx.y * 64;
    int t = threadIdx.x;
    int tr = t >> 4, tc = t & 15;
    float acc[4][4];
#pragma unroll
    for (int i = 0; i < 4; ++i)
#pragma unroll
        for (int j = 0; j < 4; ++j) acc[i][j] = 0.f;

    for (int k0 = 0; k0 < FD; k0 += 32) {
#pragma unroll
        for (int s = 0; s < 2; ++s) {
            int task = t + s * 256;
            int row = task >> 3, ch = task & 7;
            float4 v = *(const float4*)&z[(b0 + row) * FD + k0 + ch * 4];
            zT[ch * 4 + 0][row] = v.x;
            zT[ch * 4 + 1][row] = v.y;
            zT[ch * 4 + 2][row] = v.z;
            zT[ch * 4 + 3][row] = v.w;
        }
#pragma unroll
        for (int s = 0; s < 2; ++s) {
            int task = t + s * 256;
            int kr = task >> 4, cq = task & 15;
            *(float4*)&Ws[kr][cq * 4] = *(const float4*)&W12p[(k0 + kr) * NIP + c0 + cq * 4];
        }
        __syncthreads();
#pragma unroll
        for (int k = 0; k < 32; ++k) {
            float4 zb = *(const float4*)&zT[k][tr * 4];
            float4 wv = *(const float4*)&Ws[k][tc * 4];
            float zz[4] = {zb.x, zb.y, zb.z, zb.w};
            float ww[4] = {wv.x, wv.y, wv.z, wv.w};
#pragma unroll
            for (int i = 0; i < 4; ++i)
#pragma unroll
                for (int j = 0; j < 4; ++j) acc[i][j] += zz[i] * ww[j];
        }
        __syncthreads();
    }
#pragma unroll
    for (int i = 0; i < 4; ++i) {
        float4 v = make_float4(acc[i][0], acc[i][1], acc[i][2], acc[i][3]);
        *(float4*)&wout[(b0 + tr * 4 + i) * NIP + c0 + tc * 4] = v;
    }
}

// K3: one block per b, 320 threads. thread = (jg in [0,4), f, dq):
// gathers ~5 pairs x 2 heads as float4 (10 independent dwordx4 in flight),
// partial-accumulates, LDS-reduce over jg, then 32x4 transform.
#define SAC(jg, f, h, k) ((((jg) * FF + (f)) * 2 + (h)) * 17 + (k))
__global__ __launch_bounds__(320, 6) void k_main(const float* __restrict__ cb,   // [500000][16]
                                                 const float* __restrict__ Wt,   // [32][16]
                                                 const int* __restrict__ hidx,   // [2][B][NI]
                                                 const int* __restrict__ iidx,   // [20][19]
                                                 const float* __restrict__ wbuf, // [B][192]
                                                 float* __restrict__ out) {      // [B][20][16]
    __shared__ int s_i0[NI], s_i1[NI];
    __shared__ float s_w[NI];
    __shared__ int s_plist[FF * 19];
    __shared__ float s_W[32 * 16];
    __shared__ float s_acc[4 * FF * 2 * 17];

    int t = threadIdx.x;
    int b = blockIdx.x;

    if (t < NI) {
        s_i0[t] = hidx[b * NI + t];
        s_i1[t] = hidx[(BB + b) * NI + t];
        s_w[t] = wbuf[b * NIP + t];
    }
    for (int j = t; j < FF * 19; j += 320) s_plist[j] = iidx[j];
    for (int j = t; j < 512; j += 320) s_W[j] = Wt[j];
    __syncthreads();

    int jg = t / 80;           // 0..3
    int r = t % 80;
    int f = r >> 2, dq = r & 3;

    const float4* cb4 = (const float4*)cb;
    const int* pl = &s_plist[f * 19];
    float4 a0 = make_float4(0.f, 0.f, 0.f, 0.f);
    float4 a1 = make_float4(0.f, 0.f, 0.f, 0.f);
#pragma unroll
    for (int jj = 0; jj < 5; ++jj) {
        int j = jg * 5 + jj;
        if (j < 19) {
            int p = pl[j];
            float wv = s_w[p];
            float4 v0 = cb4[s_i0[p] * 4 + dq];
            float4 v1 = cb4[s_i1[p] * 4 + dq];
            a0.x += wv * v0.x; a0.y += wv * v0.y; a0.z += wv * v0.z; a0.w += wv * v0.w;
            a1.x += wv * v1.x; a1.y += wv * v1.y; a1.z += wv * v1.z; a1.w += wv * v1.w;
        }
    }
    s_acc[SAC(jg, f, 0, dq * 4 + 0)] = a0.x;
    s_acc[SAC(jg, f, 0, dq * 4 + 1)] = a0.y;
    s_acc[SAC(jg, f, 0, dq * 4 + 2)] = a0.z;
    s_acc[SAC(jg, f, 0, dq * 4 + 3)] = a0.w;
    s_acc[SAC(jg, f, 1, dq * 4 + 0)] = a1.x;
    s_acc[SAC(jg, f, 1, dq * 4 + 1)] = a1.y;
    s_acc[SAC(jg, f, 1, dq * 4 + 2)] = a1.z;
    s_acc[SAC(jg, f, 1, dq * 4 + 3)] = a1.w;
    __syncthreads();

    // reduce jg=1..3 into jg=0 slice: 320 threads x (2 heads x 4 k-values)
#pragma unroll
    for (int h = 0; h < 2; ++h) {
#pragma unroll
        for (int c = 0; c < 4; ++c) {
            int k = dq * 4 + c;
            if (jg == 0) {
                s_acc[SAC(0, f, h, k)] += s_acc[SAC(1, f, h, k)] +
                                          s_acc[SAC(2, f, h, k)] +
                                          s_acc[SAC(3, f, h, k)];
            }
        }
    }
    __syncthreads();

    if (t < 80) {
        // transform: out[b,f,dq*4+c] = sum_k acc0[k]*W[k][..] + acc1[k]*W[16+k][..]
        float4 rr = make_float4(0.f, 0.f, 0.f, 0.f);
#pragma unroll
        for (int k = 0; k < 16; ++k) {
            float c0 = s_acc[SAC(0, f, 0, k)];
            float4 wv = *(const float4*)&s_W[k * 16 + dq * 4];
            rr.x += c0 * wv.x; rr.y += c0 * wv.y; rr.z += c0 * wv.z; rr.w += c0 * wv.w;
        }
#pragma unroll
        for (int k = 0; k < 16; ++k) {
            float c1 = s_acc[SAC(0, f, 1, k)];
            float4 wv = *(const float4*)&s_W[(16 + k) * 16 + dq * 4];
            rr.x += c1 * wv.x; rr.y += c1 * wv.y; rr.z += c1 * wv.z; rr.w += c1 * wv.w;
        }
        *(float4*)&out[b * FD + f * 16 + dq * 4] = rr;
    }
}

extern "C" void kernel_launch(void* const* d_in, const int* in_sizes, int n_in,
                              void* d_out, int out_size, void* d_ws, size_t ws_size,
                              hipStream_t stream) {
    const float* origin = (const float*)d_in[0];  // (B, F, D) = z
    const float* cb     = (const float*)d_in[1];  // (500000, 16)
    const float* Wt     = (const float*)d_in[2];  // (32, 16)
    const float* w1     = (const float*)d_in[3];  // (320, 320)
    const float* w2     = (const float*)d_in[4];  // (320, 190)
    const int*   hidx   = (const int*)d_in[5];    // (2, B, 190)
    const int*   iidx   = (const int*)d_in[6];    // (20, 19)
    float* out = (float*)d_out;

    float* W12p = (float*)d_ws;           // 320*192 floats
    float* wbuf = W12p + FD * NIP;        // 4096*192 floats

    k_w12<<<FD, 192, 0, stream>>>(w1, w2, W12p);
    dim3 gw(BB / 64, 3);
    k_w<<<gw, 256, 0, stream>>>(origin, W12p, wbuf);
    k_main<<<BB, 320, 0, stream>>>(cb, Wt, hidx, iidx, wbuf, out);
}